// Round 7
// baseline (652.224 us; speedup 1.0000x reference)
//
#include <hip/hip_runtime.h>
#include <hip/hip_bf16.h>

typedef __hip_bfloat16 bf16;
typedef __attribute__((ext_vector_type(8))) __bf16 bf16x8;
typedef __attribute__((ext_vector_type(4))) float f32x4;

#define MFMA16(a, b, c) __builtin_amdgcn_mfma_f32_16x16x32_bf16((a), (b), (c), 0, 0, 0)

#define BT 4096      // B*T rows
#define CE 2048      // embed dim
#define NQKV 3072    // q(2048) + k(512) + v(512)
#define TSEQ 2048
#define HD 128

// q pre-scale: 1/sqrt(128) * log2(e), folded into rope_rms's q output.
#define QSCALE (0.08838834764831845f * 1.4426950408889634f)
// fixed softmax max bound: ||q'||*||k|| = 128*QSCALE (Cauchy-Schwarz on
// RMS-normalized vectors). p = 2^(s' - M2) <= ~1, no online max needed.
#define M2 16.3222f

// ---------------------------------------------------------------------------
// async global->LDS 16B copy (one instruction, no VGPR round trip)
__device__ __forceinline__ void gld16(const void* g, void* l)
{
    __builtin_amdgcn_global_load_lds(
        (const __attribute__((address_space(1))) void*)g,
        (__attribute__((address_space(3))) void*)l, 16, 0, 0);
}

// ---------------------------------------------------------------------------
// Input-dtype detector (R4-confirmed: inputs are fp32; gate kept for safety).
__global__ void detect_dtype(const unsigned short* __restrict__ x, int* __restrict__ flag)
{
    __shared__ int cnt;
    if (threadIdx.x == 0) cnt = 0;
    __syncthreads();
    unsigned short w = x[2 * threadIdx.x];
    int e = (w >> 7) & 0xFF;
    atomicAdd(&cnt, (e >= 117 && e <= 130) ? 1 : 0);
    __syncthreads();
    if (threadIdx.x == 0) *flag = (cnt < 128) ? 1 : 0;
}

// Stage 8 elems (16B bf16) into LDS from bf16 or fp32 source (VGPR convert).
__device__ __forceinline__ void stage8(short* dst, const void* src, size_t eoff, bool f32)
{
    if (f32) {
        const float* s = (const float*)src + eoff;
        float4 f0 = *(const float4*)s;
        float4 f1 = *(const float4*)(s + 4);
        bf16x8 v;
        v[0] = (__bf16)f0.x; v[1] = (__bf16)f0.y; v[2] = (__bf16)f0.z; v[3] = (__bf16)f0.w;
        v[4] = (__bf16)f1.x; v[5] = (__bf16)f1.y; v[6] = (__bf16)f1.z; v[7] = (__bf16)f1.w;
        *(bf16x8*)dst = v;
    } else {
        *(uint4*)dst = *(const uint4*)((const bf16*)src + eoff);
    }
}

__device__ __forceinline__ float ldf(const void* p, int i, bool f32)
{
    return f32 ? ((const float*)p)[i] : __bfloat162float(((const bf16*)p)[i]);
}

// ---------------------------------------------------------------------------
// fp32 (or bf16) -> bf16 conversion, 8 elems/thread.
__global__ __launch_bounds__(256)
void conv_bf16(const void* __restrict__ src, bf16* __restrict__ dst,
               const int* __restrict__ flagp)
{
    const bool f = *flagp != 0;
    size_t i8 = (size_t)blockIdx.x * 256 + threadIdx.x;
    stage8((short*)(dst + i8 * 8), src, i8 * 8, f);
}

// ---------------------------------------------------------------------------
// C[M,N] = A[M,K] @ W[N,K]^T, fp32 accum. (unchanged from R6)
__global__ __launch_bounds__(256)
void gemm_bt(const void* __restrict__ A, const bf16* __restrict__ W,
             void* __restrict__ C, int M, int N, int K, int lda,
             int aGate, int oGate, const int* __restrict__ flagp)
{
    __shared__ short As[128][32];
    __shared__ short Bs[128][32];

    const int f = *flagp;
    const bool aF = aGate && f, oF = oGate && f;

    const int tid   = threadIdx.x;
    const int lane  = tid & 63;
    const int wid   = tid >> 6;
    const int row16 = lane & 15;
    const int quad  = lane >> 4;
    const int wr    = wid >> 1;
    const int wc    = wid & 1;
    const int m0    = blockIdx.y * 128;
    const int n0    = blockIdx.x * 128;

    const int rl4 = wid * 16 + (lane >> 2);
    const int c8  = (lane & 3) * 8;

    f32x4 acc[4][4];
#pragma unroll
    for (int i = 0; i < 4; i++)
#pragma unroll
        for (int j = 0; j < 4; j++)
            acc[i][j] = (f32x4){0.f, 0.f, 0.f, 0.f};

    for (int k0 = 0; k0 < K; k0 += 32) {
#pragma unroll
        for (int i = 0; i < 2; i++) {
            int r = i * 64 + rl4;
            gld16(W + (size_t)(n0 + r) * K + k0 + c8, &Bs[r][c8]);
        }
        if (!aF) {
#pragma unroll
            for (int i = 0; i < 2; i++) {
                int r = i * 64 + rl4;
                gld16((const bf16*)A + (size_t)(m0 + r) * lda + k0 + c8, &As[r][c8]);
            }
        } else {
#pragma unroll
            for (int i = 0; i < 2; i++) {
                int c = i * 256 + tid;
                int row = c >> 2, col = (c & 3) << 3;
                stage8(&As[row][col], A, (size_t)(m0 + row) * lda + k0 + col, true);
            }
        }
        __syncthreads();

        bf16x8 af[4], bfv[4];
#pragma unroll
        for (int mi = 0; mi < 4; mi++)
            af[mi] = *(const bf16x8*)&As[wr * 64 + mi * 16 + row16][quad * 8];
#pragma unroll
        for (int ni = 0; ni < 4; ni++)
            bfv[ni] = *(const bf16x8*)&Bs[wc * 64 + ni * 16 + row16][quad * 8];
#pragma unroll
        for (int mi = 0; mi < 4; mi++)
#pragma unroll
            for (int ni = 0; ni < 4; ni++)
                acc[mi][ni] = MFMA16(af[mi], bfv[ni], acc[mi][ni]);
        __syncthreads();
    }

#pragma unroll
    for (int mi = 0; mi < 4; mi++) {
        int rowb = m0 + wr * 64 + mi * 16 + quad * 4;
#pragma unroll
        for (int ni = 0; ni < 4; ni++) {
            int col = n0 + wc * 64 + ni * 16 + row16;
#pragma unroll
            for (int r = 0; r < 4; r++) {
                size_t idx = (size_t)(rowb + r) * N + col;
                float  v   = acc[mi][ni][r];
                if (oF) ((float*)C)[idx] = v;
                else    ((bf16*)C)[idx]  = __float2bfloat16(v);
            }
        }
    }
}

// ---------------------------------------------------------------------------
// RoPE + RMSNorm in place in qkv; q additionally scaled by QSCALE. (unchanged)
__global__ __launch_bounds__(256)
void rope_rms(bf16* __restrict__ qkv, const void* __restrict__ cosp,
              const void* __restrict__ sinp, const int* __restrict__ flagp)
{
    const bool f = *flagp != 0;
    const int wg   = blockIdx.x * 4 + (threadIdx.x >> 6);
    const int lane = threadIdx.x & 63;
    const int s    = wg % 20;
    const int m    = wg / 20;
    const int t    = m & (TSEQ - 1);

    const int col = (s < 16) ? s * HD : CE + (s - 16) * HD;
    bf16* p = qkv + (size_t)m * NQKV + col;

    float xlo = __bfloat162float(p[lane]);
    float xhi = __bfloat162float(p[lane + 64]);
    float cl  = ldf(cosp, t * HD + lane, f);
    float sl  = ldf(sinp, t * HD + lane, f);
    float ch  = ldf(cosp, t * HD + 64 + lane, f);
    float sh  = ldf(sinp, t * HD + 64 + lane, f);

    float rlo = xlo * cl - xhi * sl;
    float rhi = xhi * ch + xlo * sh;

    float ss = rlo * rlo + rhi * rhi;
#pragma unroll
    for (int off = 32; off > 0; off >>= 1)
        ss += __shfl_xor(ss, off, 64);
    float inv = rsqrtf(ss * (1.0f / 128.0f) + 1.1920929e-07f);
    if (s < 16) inv *= QSCALE;

    p[lane]      = __float2bfloat16(rlo * inv);
    p[lane + 64] = __float2bfloat16(rhi * inv);
}

// ---------------------------------------------------------------------------
// vt[b, hk, d, t] = qkv[(b*T+t)*3072 + 2560 + hk*128 + d]  (unchanged)
__global__ __launch_bounds__(256)
void vtrans(const bf16* __restrict__ qkv, bf16* __restrict__ vt)
{
    int idx = blockIdx.x * 256 + threadIdx.x;
    int t  = idx & (TSEQ - 1);
    int d  = (idx >> 11) & 127;
    int bh = idx >> 18;
    vt[idx] = qkv[((size_t)((bh >> 2) * TSEQ + t)) * NQKV + 2560 + (bh & 3) * HD + d];
}

// ---------------------------------------------------------------------------
// Flash attention (R7): fixed-max softmax (R6) + NATURAL block order
// (R6's reversal regressed 192->241us -> reverted) + register prefetch of
// the next K/V tile. Prefetch is issued AFTER the second barrier so its
// latency is hidden behind the compute phase; the conservative vmcnt(0)
// drain at the next iteration's first barrier then completes quickly.
__global__ __launch_bounds__(256)
void attn(bf16* __restrict__ qkv, const bf16* __restrict__ vt)
{
    __shared__ __bf16 Ks[64][136];
    __shared__ __bf16 Vs[128][72];
    __shared__ __bf16 Pl[4][16][72];

    const int tid   = threadIdx.x;
    const int lane  = tid & 63;
    const int wid   = tid >> 6;
    const int row16 = lane & 15;
    const int quad  = lane >> 4;
    const int b  = blockIdx.y >> 4;
    const int h  = blockIdx.y & 15;
    const int hk = h >> 2;
    const int xi = blockIdx.x;            // natural order
    const int q0 = xi * 64 + wid * 16;

    const bf16* Q  = qkv + ((size_t)(b * TSEQ + q0)) * NQKV + h * HD;
    const bf16* Kp = qkv + ((size_t)(b * TSEQ)) * NQKV + CE + hk * HD;
    const bf16* Vp = vt + ((size_t)(b * 4 + hk) * HD) * TSEQ;

    bf16x8 aq[4];
#pragma unroll
    for (int ds = 0; ds < 4; ds++)
        aq[ds] = *(const bf16x8*)(Q + (size_t)row16 * NQKV + ds * 32 + quad * 8);

    f32x4 o[8];
#pragma unroll
    for (int dt = 0; dt < 8; dt++) o[dt] = (f32x4){0.f, 0.f, 0.f, 0.f};
    float lsum[4] = {0.f, 0.f, 0.f, 0.f};

    // staging geometry (per thread: 4 rows of K, 4 rows of V^T, 16B each)
    const int krow = tid >> 4;          // 0..15
    const int kcol = (tid & 15) * 8;
    const int vrow = tid >> 3;          // 0..31
    const int vcol = (tid & 7) * 8;

    // preload tile 0 into registers
    uint4 kreg[4], vreg[4];
#pragma unroll
    for (int p4 = 0; p4 < 4; p4++)
        kreg[p4] = *(const uint4*)(Kp + (size_t)(p4 * 16 + krow) * NQKV + kcol);
#pragma unroll
    for (int p4 = 0; p4 < 4; p4++)
        vreg[p4] = *(const uint4*)(Vp + (size_t)(p4 * 32 + vrow) * TSEQ + vcol);

    for (int t = 0; t <= xi; t++) {
        const int k0 = t * 64;
        const bool diag = (t == xi);

        __syncthreads();   // prior compute's LDS reads done (+ drains prefetch)
#pragma unroll
        for (int p4 = 0; p4 < 4; p4++)
            *(uint4*)&Ks[p4 * 16 + krow][kcol] = kreg[p4];
#pragma unroll
        for (int p4 = 0; p4 < 4; p4++)
            *(uint4*)&Vs[p4 * 32 + vrow][vcol] = vreg[p4];
        __syncthreads();

        // issue next tile's loads now: latency hidden behind compute below
        {
            const int kn = diag ? k0 : k0 + 64;   // clamp: last iter reloads (unused)
#pragma unroll
            for (int p4 = 0; p4 < 4; p4++)
                kreg[p4] = *(const uint4*)(Kp + (size_t)(kn + p4 * 16 + krow) * NQKV + kcol);
#pragma unroll
            for (int p4 = 0; p4 < 4; p4++)
                vreg[p4] = *(const uint4*)(Vp + (size_t)(p4 * 32 + vrow) * TSEQ + kn + vcol);
        }

        // QK^T: 4 key-groups of 16
        f32x4 s[4];
#pragma unroll
        for (int kg = 0; kg < 4; kg++) s[kg] = (f32x4){0.f, 0.f, 0.f, 0.f};
#pragma unroll
        for (int ds = 0; ds < 4; ds++) {
#pragma unroll
            for (int kg = 0; kg < 4; kg++) {
                bf16x8 kf = *(const bf16x8*)&Ks[kg * 16 + row16][ds * 32 + quad * 8];
                s[kg] = MFMA16(aq[ds], kf, s[kg]);
            }
        }

        // fixed-max softmax numerators; per-lane partial sums
#pragma unroll
        for (int r = 0; r < 4; r++) {
            float p[4];
            if (diag) {
                int qrow = q0 + quad * 4 + r;
#pragma unroll
                for (int kg = 0; kg < 4; kg++)
                    p[kg] = (k0 + kg * 16 + row16 <= qrow)
                          ? __builtin_amdgcn_exp2f(s[kg][r] - M2) : 0.f;
            } else {
#pragma unroll
                for (int kg = 0; kg < 4; kg++)
                    p[kg] = __builtin_amdgcn_exp2f(s[kg][r] - M2);
            }
            lsum[r] += (p[0] + p[1]) + (p[2] + p[3]);
#pragma unroll
            for (int kg = 0; kg < 4; kg++)
                Pl[wid][quad * 4 + r][kg * 16 + row16] = (__bf16)p[kg];
        }

        // C-layout -> A-layout via wave-private LDS (fences pin ordering)
        __asm__ volatile("" ::: "memory");
#pragma unroll
        for (int c = 0; c < 2; c++) {
            bf16x8 pf = *(const bf16x8*)&Pl[wid][row16][c * 32 + quad * 8];
#pragma unroll
            for (int dt = 0; dt < 8; dt++) {
                bf16x8 vf = *(const bf16x8*)&Vs[dt * 16 + row16][c * 32 + quad * 8];
                o[dt] = MFMA16(pf, vf, o[dt]);
            }
        }
        __asm__ volatile("" ::: "memory");
    }

    // final 16-lane reduction of l per row; write O into qkv's Q slot
#pragma unroll
    for (int r = 0; r < 4; r++) {
        float l = lsum[r];
#pragma unroll
        for (int off = 1; off < 16; off <<= 1)
            l += __shfl_xor(l, off, 64);
        float rl = 1.0f / l;
        int t = q0 + quad * 4 + r;
        bf16* dst = qkv + ((size_t)(b * TSEQ + t)) * NQKV + h * HD;
#pragma unroll
        for (int dt = 0; dt < 8; dt++)
            dst[dt * 16 + row16] = __float2bfloat16(o[dt][r] * rl);
    }
}

// ---------------------------------------------------------------------------
extern "C" void kernel_launch(void* const* d_in, const int* in_sizes, int n_in,
                              void* d_out, int out_size, void* d_ws, size_t ws_size,
                              hipStream_t stream)
{
    // ws (bf16 elems): qkv [4096,3072] 25.2MB | vt 4.2MB | wqkvb [3072,2048]
    // 12.6MB (reused for wprojb after gemm1) | flag. ~42MB.
    bf16* qkv   = (bf16*)d_ws;
    bf16* vt    = qkv + (size_t)BT * NQKV;
    bf16* wqkvb = vt + (size_t)2 * 4 * HD * TSEQ;
    int* flagp  = (int*)(wqkvb + (size_t)NQKV * CE);

    // 0) detect input dtype -> device flag
    detect_dtype<<<1, 256, 0, stream>>>((const unsigned short*)d_in[0], flagp);

    // 1) convert wq/wk/wv to fused bf16 [3072][2048]
    conv_bf16<<<(2048 * 2048 / 8) / 256, 256, 0, stream>>>(d_in[3], wqkvb, flagp);
    conv_bf16<<<(512 * 2048 / 8) / 256, 256, 0, stream>>>(d_in[4], wqkvb + (size_t)2048 * 2048, flagp);
    conv_bf16<<<(512 * 2048 / 8) / 256, 256, 0, stream>>>(d_in[5], wqkvb + (size_t)2560 * 2048, flagp);

    // 2) fused QKV projection
    gemm_bt<<<dim3(NQKV / 128, BT / 128), 256, 0, stream>>>(
        d_in[0], wqkvb, qkv, BT, NQKV, CE, CE, 1, 0, flagp);

    // 3) convert wproj into the same buffer (stream-ordered after gemm1)
    conv_bf16<<<(2048 * 2048 / 8) / 256, 256, 0, stream>>>(d_in[6], wqkvb, flagp);

    // 4) V transpose to [B,KV,D,T]
    vtrans<<<(2 * 4 * HD * TSEQ) / 256, 256, 0, stream>>>(qkv, vt);

    // 5) RoPE + RMSNorm in place (q scaled by QSCALE)
    rope_rms<<<(BT * 20) / 4, 256, 0, stream>>>(qkv, d_in[1], d_in[2], flagp);

    // 6) flash attention; O overwrites qkv's Q columns
    attn<<<dim3(TSEQ / 64, 2 * 16), 256, 0, stream>>>(qkv, vt);

    // 7) output projection: A=qkv cols 0..2047 (bf16, lda=3072, async DMA)
    gemm_bt<<<dim3(CE / 128, BT / 128), 256, 0, stream>>>(
        qkv, wqkvb, d_out, BT, CE, CE, NQKV, 0, 1, flagp);
}

// Round 8
// 506.908 us; speedup vs baseline: 1.2867x; 1.2867x over previous
//
#include <hip/hip_runtime.h>
#include <hip/hip_bf16.h>

typedef __hip_bfloat16 bf16;
typedef __attribute__((ext_vector_type(8))) __bf16 bf16x8;
typedef __attribute__((ext_vector_type(4))) float f32x4;

#define MFMA16(a, b, c) __builtin_amdgcn_mfma_f32_16x16x32_bf16((a), (b), (c), 0, 0, 0)

#define BT 4096      // B*T rows
#define CE 2048      // embed dim
#define NQKV 3072    // q(2048) + k(512) + v(512)
#define TSEQ 2048
#define HD 128

// q pre-scale: 1/sqrt(128) * log2(e), folded into rope_rms's q output.
#define QSCALE (0.08838834764831845f * 1.4426950408889634f)
// fixed softmax max bound: ||q'||*||k|| = 128*QSCALE (Cauchy-Schwarz on
// RMS-normalized vectors). p = 2^(s' - M2) <= ~1, no online max needed.
#define M2 16.3222f

// ---------------------------------------------------------------------------
// async global->LDS 16B copy (one instruction, no VGPR round trip)
__device__ __forceinline__ void gld16(const void* g, void* l)
{
    __builtin_amdgcn_global_load_lds(
        (const __attribute__((address_space(1))) void*)g,
        (__attribute__((address_space(3))) void*)l, 16, 0, 0);
}

// ---------------------------------------------------------------------------
// Input-dtype detector (R4-confirmed: inputs are fp32; gate kept for safety).
__global__ void detect_dtype(const unsigned short* __restrict__ x, int* __restrict__ flag)
{
    __shared__ int cnt;
    if (threadIdx.x == 0) cnt = 0;
    __syncthreads();
    unsigned short w = x[2 * threadIdx.x];
    int e = (w >> 7) & 0xFF;
    atomicAdd(&cnt, (e >= 117 && e <= 130) ? 1 : 0);
    __syncthreads();
    if (threadIdx.x == 0) *flag = (cnt < 128) ? 1 : 0;
}

// Stage 8 elems (16B bf16) into LDS from bf16 or fp32 source (VGPR convert).
__device__ __forceinline__ void stage8(short* dst, const void* src, size_t eoff, bool f32)
{
    if (f32) {
        const float* s = (const float*)src + eoff;
        float4 f0 = *(const float4*)s;
        float4 f1 = *(const float4*)(s + 4);
        bf16x8 v;
        v[0] = (__bf16)f0.x; v[1] = (__bf16)f0.y; v[2] = (__bf16)f0.z; v[3] = (__bf16)f0.w;
        v[4] = (__bf16)f1.x; v[5] = (__bf16)f1.y; v[6] = (__bf16)f1.z; v[7] = (__bf16)f1.w;
        *(bf16x8*)dst = v;
    } else {
        *(uint4*)dst = *(const uint4*)((const bf16*)src + eoff);
    }
}

__device__ __forceinline__ float ldf(const void* p, int i, bool f32)
{
    return f32 ? ((const float*)p)[i] : __bfloat162float(((const bf16*)p)[i]);
}

// ---------------------------------------------------------------------------
// fp32 (or bf16) -> bf16 conversion, 8 elems/thread.
__global__ __launch_bounds__(256)
void conv_bf16(const void* __restrict__ src, bf16* __restrict__ dst,
               const int* __restrict__ flagp)
{
    const bool f = *flagp != 0;
    size_t i8 = (size_t)blockIdx.x * 256 + threadIdx.x;
    stage8((short*)(dst + i8 * 8), src, i8 * 8, f);
}

// ---------------------------------------------------------------------------
// C[M,N] = A[M,K] @ W[N,K]^T, fp32 accum. (unchanged from R6)
__global__ __launch_bounds__(256)
void gemm_bt(const void* __restrict__ A, const bf16* __restrict__ W,
             void* __restrict__ C, int M, int N, int K, int lda,
             int aGate, int oGate, const int* __restrict__ flagp)
{
    __shared__ short As[128][32];
    __shared__ short Bs[128][32];

    const int f = *flagp;
    const bool aF = aGate && f, oF = oGate && f;

    const int tid   = threadIdx.x;
    const int lane  = tid & 63;
    const int wid   = tid >> 6;
    const int row16 = lane & 15;
    const int quad  = lane >> 4;
    const int wr    = wid >> 1;
    const int wc    = wid & 1;
    const int m0    = blockIdx.y * 128;
    const int n0    = blockIdx.x * 128;

    const int rl4 = wid * 16 + (lane >> 2);
    const int c8  = (lane & 3) * 8;

    f32x4 acc[4][4];
#pragma unroll
    for (int i = 0; i < 4; i++)
#pragma unroll
        for (int j = 0; j < 4; j++)
            acc[i][j] = (f32x4){0.f, 0.f, 0.f, 0.f};

    for (int k0 = 0; k0 < K; k0 += 32) {
#pragma unroll
        for (int i = 0; i < 2; i++) {
            int r = i * 64 + rl4;
            gld16(W + (size_t)(n0 + r) * K + k0 + c8, &Bs[r][c8]);
        }
        if (!aF) {
#pragma unroll
            for (int i = 0; i < 2; i++) {
                int r = i * 64 + rl4;
                gld16((const bf16*)A + (size_t)(m0 + r) * lda + k0 + c8, &As[r][c8]);
            }
        } else {
#pragma unroll
            for (int i = 0; i < 2; i++) {
                int c = i * 256 + tid;
                int row = c >> 2, col = (c & 3) << 3;
                stage8(&As[row][col], A, (size_t)(m0 + row) * lda + k0 + col, true);
            }
        }
        __syncthreads();

        bf16x8 af[4], bfv[4];
#pragma unroll
        for (int mi = 0; mi < 4; mi++)
            af[mi] = *(const bf16x8*)&As[wr * 64 + mi * 16 + row16][quad * 8];
#pragma unroll
        for (int ni = 0; ni < 4; ni++)
            bfv[ni] = *(const bf16x8*)&Bs[wc * 64 + ni * 16 + row16][quad * 8];
#pragma unroll
        for (int mi = 0; mi < 4; mi++)
#pragma unroll
            for (int ni = 0; ni < 4; ni++)
                acc[mi][ni] = MFMA16(af[mi], bfv[ni], acc[mi][ni]);
        __syncthreads();
    }

#pragma unroll
    for (int mi = 0; mi < 4; mi++) {
        int rowb = m0 + wr * 64 + mi * 16 + quad * 4;
#pragma unroll
        for (int ni = 0; ni < 4; ni++) {
            int col = n0 + wc * 64 + ni * 16 + row16;
#pragma unroll
            for (int r = 0; r < 4; r++) {
                size_t idx = (size_t)(rowb + r) * N + col;
                float  v   = acc[mi][ni][r];
                if (oF) ((float*)C)[idx] = v;
                else    ((bf16*)C)[idx]  = __float2bfloat16(v);
            }
        }
    }
}

// ---------------------------------------------------------------------------
// RoPE + RMSNorm in place in qkv; q additionally scaled by QSCALE. (unchanged)
__global__ __launch_bounds__(256)
void rope_rms(bf16* __restrict__ qkv, const void* __restrict__ cosp,
              const void* __restrict__ sinp, const int* __restrict__ flagp)
{
    const bool f = *flagp != 0;
    const int wg   = blockIdx.x * 4 + (threadIdx.x >> 6);
    const int lane = threadIdx.x & 63;
    const int s    = wg % 20;
    const int m    = wg / 20;
    const int t    = m & (TSEQ - 1);

    const int col = (s < 16) ? s * HD : CE + (s - 16) * HD;
    bf16* p = qkv + (size_t)m * NQKV + col;

    float xlo = __bfloat162float(p[lane]);
    float xhi = __bfloat162float(p[lane + 64]);
    float cl  = ldf(cosp, t * HD + lane, f);
    float sl  = ldf(sinp, t * HD + lane, f);
    float ch  = ldf(cosp, t * HD + 64 + lane, f);
    float sh  = ldf(sinp, t * HD + 64 + lane, f);

    float rlo = xlo * cl - xhi * sl;
    float rhi = xhi * ch + xlo * sh;

    float ss = rlo * rlo + rhi * rhi;
#pragma unroll
    for (int off = 32; off > 0; off >>= 1)
        ss += __shfl_xor(ss, off, 64);
    float inv = rsqrtf(ss * (1.0f / 128.0f) + 1.1920929e-07f);
    if (s < 16) inv *= QSCALE;

    p[lane]      = __float2bfloat16(rlo * inv);
    p[lane + 64] = __float2bfloat16(rhi * inv);
}

// ---------------------------------------------------------------------------
// vt[b, hk, d, t] = qkv[(b*T+t)*3072 + 2560 + hk*128 + d]  (unchanged)
__global__ __launch_bounds__(256)
void vtrans(const bf16* __restrict__ qkv, bf16* __restrict__ vt)
{
    int idx = blockIdx.x * 256 + threadIdx.x;
    int t  = idx & (TSEQ - 1);
    int d  = (idx >> 11) & 127;
    int bh = idx >> 18;
    vt[idx] = qkv[((size_t)((bh >> 2) * TSEQ + t)) * NQKV + 2560 + (bh & 3) * HD + d];
}

// ---------------------------------------------------------------------------
// Flash attention (R8): R6's body EXCEPT natural block order. Single-variable
// test of the ordering hypothesis. No register prefetch (R7's spilled to
// scratch: WRITE_SIZE 16->284MB). Direct uint4 global->LDS staging per tile;
// fixed-max softmax; O in place into qkv's Q columns.
__global__ __launch_bounds__(256)
void attn(bf16* __restrict__ qkv, const bf16* __restrict__ vt)
{
    __shared__ __bf16 Ks[64][136];
    __shared__ __bf16 Vs[128][72];
    __shared__ __bf16 Pl[4][16][72];

    const int tid   = threadIdx.x;
    const int lane  = tid & 63;
    const int wid   = tid >> 6;
    const int row16 = lane & 15;
    const int quad  = lane >> 4;
    const int b  = blockIdx.y >> 4;
    const int h  = blockIdx.y & 15;
    const int hk = h >> 2;
    const int xi = blockIdx.x;            // natural order (R6 reversal reverted)
    const int q0 = xi * 64 + wid * 16;

    const bf16* Q  = qkv + ((size_t)(b * TSEQ + q0)) * NQKV + h * HD;
    const bf16* Kp = qkv + ((size_t)(b * TSEQ)) * NQKV + CE + hk * HD;
    const bf16* Vp = vt + ((size_t)(b * 4 + hk) * HD) * TSEQ;

    bf16x8 aq[4];
#pragma unroll
    for (int ds = 0; ds < 4; ds++)
        aq[ds] = *(const bf16x8*)(Q + (size_t)row16 * NQKV + ds * 32 + quad * 8);

    f32x4 o[8];
#pragma unroll
    for (int dt = 0; dt < 8; dt++) o[dt] = (f32x4){0.f, 0.f, 0.f, 0.f};
    float lsum[4] = {0.f, 0.f, 0.f, 0.f};

    for (int t = 0; t <= xi; t++) {
        const int k0 = t * 64;
        const bool diag = (t == xi);

        __syncthreads();   // prior iteration's LDS reads complete
#pragma unroll
        for (int p4 = 0; p4 < 4; p4++) {
            int row = p4 * 16 + (tid >> 4);
            int col = (tid & 15) * 8;
            *(uint4*)&Ks[row][col] =
                *(const uint4*)(Kp + (size_t)(k0 + row) * NQKV + col);
        }
#pragma unroll
        for (int p4 = 0; p4 < 4; p4++) {
            int row = p4 * 32 + (tid >> 3);
            int col = (tid & 7) * 8;
            *(uint4*)&Vs[row][col] =
                *(const uint4*)(Vp + (size_t)row * TSEQ + k0 + col);
        }
        __syncthreads();

        // QK^T: 4 key-groups of 16
        f32x4 s[4];
#pragma unroll
        for (int kg = 0; kg < 4; kg++) s[kg] = (f32x4){0.f, 0.f, 0.f, 0.f};
#pragma unroll
        for (int ds = 0; ds < 4; ds++) {
#pragma unroll
            for (int kg = 0; kg < 4; kg++) {
                bf16x8 kf = *(const bf16x8*)&Ks[kg * 16 + row16][ds * 32 + quad * 8];
                s[kg] = MFMA16(aq[ds], kf, s[kg]);
            }
        }

        // fixed-max softmax numerators; per-lane partial sums
#pragma unroll
        for (int r = 0; r < 4; r++) {
            float p[4];
            if (diag) {
                int qrow = q0 + quad * 4 + r;
#pragma unroll
                for (int kg = 0; kg < 4; kg++)
                    p[kg] = (k0 + kg * 16 + row16 <= qrow)
                          ? __builtin_amdgcn_exp2f(s[kg][r] - M2) : 0.f;
            } else {
#pragma unroll
                for (int kg = 0; kg < 4; kg++)
                    p[kg] = __builtin_amdgcn_exp2f(s[kg][r] - M2);
            }
            lsum[r] += (p[0] + p[1]) + (p[2] + p[3]);
#pragma unroll
            for (int kg = 0; kg < 4; kg++)
                Pl[wid][quad * 4 + r][kg * 16 + row16] = (__bf16)p[kg];
        }

        // C-layout -> A-layout via wave-private LDS (fences pin ordering)
        __asm__ volatile("" ::: "memory");
#pragma unroll
        for (int c = 0; c < 2; c++) {
            bf16x8 pf = *(const bf16x8*)&Pl[wid][row16][c * 32 + quad * 8];
#pragma unroll
            for (int dt = 0; dt < 8; dt++) {
                bf16x8 vf = *(const bf16x8*)&Vs[dt * 16 + row16][c * 32 + quad * 8];
                o[dt] = MFMA16(pf, vf, o[dt]);
            }
        }
        __asm__ volatile("" ::: "memory");
    }

    // final 16-lane reduction of l per row; write O into qkv's Q slot
#pragma unroll
    for (int r = 0; r < 4; r++) {
        float l = lsum[r];
#pragma unroll
        for (int off = 1; off < 16; off <<= 1)
            l += __shfl_xor(l, off, 64);
        float rl = 1.0f / l;
        int t = q0 + quad * 4 + r;
        bf16* dst = qkv + ((size_t)(b * TSEQ + t)) * NQKV + h * HD;
#pragma unroll
        for (int dt = 0; dt < 8; dt++)
            dst[dt * 16 + row16] = __float2bfloat16(o[dt][r] * rl);
    }
}

// ---------------------------------------------------------------------------
extern "C" void kernel_launch(void* const* d_in, const int* in_sizes, int n_in,
                              void* d_out, int out_size, void* d_ws, size_t ws_size,
                              hipStream_t stream)
{
    // ws (bf16 elems): qkv [4096,3072] 25.2MB | vt 4.2MB | wqkvb [3072,2048]
    // 12.6MB (reused for wprojb after gemm1) | flag. ~42MB.
    bf16* qkv   = (bf16*)d_ws;
    bf16* vt    = qkv + (size_t)BT * NQKV;
    bf16* wqkvb = vt + (size_t)2 * 4 * HD * TSEQ;
    int* flagp  = (int*)(wqkvb + (size_t)NQKV * CE);

    // 0) detect input dtype -> device flag
    detect_dtype<<<1, 256, 0, stream>>>((const unsigned short*)d_in[0], flagp);

    // 1) convert wq/wk/wv to fused bf16 [3072][2048]
    conv_bf16<<<(2048 * 2048 / 8) / 256, 256, 0, stream>>>(d_in[3], wqkvb, flagp);
    conv_bf16<<<(512 * 2048 / 8) / 256, 256, 0, stream>>>(d_in[4], wqkvb + (size_t)2048 * 2048, flagp);
    conv_bf16<<<(512 * 2048 / 8) / 256, 256, 0, stream>>>(d_in[5], wqkvb + (size_t)2560 * 2048, flagp);

    // 2) fused QKV projection
    gemm_bt<<<dim3(NQKV / 128, BT / 128), 256, 0, stream>>>(
        d_in[0], wqkvb, qkv, BT, NQKV, CE, CE, 1, 0, flagp);

    // 3) convert wproj into the same buffer (stream-ordered after gemm1)
    conv_bf16<<<(2048 * 2048 / 8) / 256, 256, 0, stream>>>(d_in[6], wqkvb, flagp);

    // 4) V transpose to [B,KV,D,T]
    vtrans<<<(2 * 4 * HD * TSEQ) / 256, 256, 0, stream>>>(qkv, vt);

    // 5) RoPE + RMSNorm in place (q scaled by QSCALE)
    rope_rms<<<(BT * 20) / 4, 256, 0, stream>>>(qkv, d_in[1], d_in[2], flagp);

    // 6) flash attention; O overwrites qkv's Q columns
    attn<<<dim3(TSEQ / 64, 2 * 16), 256, 0, stream>>>(qkv, vt);

    // 7) output projection: A=qkv cols 0..2047 (bf16, lda=3072, async DMA)
    gemm_bt<<<dim3(CE / 128, BT / 128), 256, 0, stream>>>(
        qkv, wqkvb, d_out, BT, CE, CE, NQKV, 0, 1, flagp);
}